// Round 8
// baseline (135.338 us; speedup 1.0000x reference)
//
#include <hip/hip_runtime.h>

// LSTM: B=1024, T=128, H=256, C=10.
// Round 8: 256 blocks x 512 thr, BB=4. Wh int8 in AGPRs, inline-asm
// v_mfma_i32_16x16x64_i8 ("a" B-operand). Single int8 h (validated, absmax 0.0).
// NEW vs r7: (1) software-pipelined step: ut1's MFMA chunks interleaved with ut0's
// epilogue VALU in source order so the VALU hides under the matrix-pipe phase;
// (2) t=0 peeled (no per-step branch); (3) h k-layout permuted (p = w*32+l16*2+ut,
// folded into pack_w) so each lane's two h bytes are adjacent -> one ds_write_b16.

#define TSTEPS  128
#define HDIM    256
#define NCLS    10
#define BB      4
#define NBLOCKS 256
#define NTHR    512

#define XSTR    132                 // floats per x row
#define HSTR    320                 // bytes per h row (2-way on b128 reads = free)
#define PSTR    260

typedef char  i8x16 __attribute__((ext_vector_type(16)));
typedef int   i32x4 __attribute__((ext_vector_type(4)));

#define L2E     1.4426950408889634f
#define MGC     (-2.0f * L2E)
#define SMG     (-2.0f * L2E / 16129.0f)   // acc scale, tanh gate (1/(127*127))
#define SMS     (-1.0f * L2E / 16129.0f)   // acc scale, sigmoid gates

static __device__ __forceinline__ float rcpf(float x) { return __builtin_amdgcn_rcpf(x); }
static __device__ __forceinline__ float exp2f_fast(float x) { return __builtin_amdgcn_exp2f(x); }

#define MFMA_I8(ACC, A, B) \
    asm("v_mfma_i32_16x16x64_i8 %0, %1, %2, %0" : "+v"(ACC) : "v"(A), "a"(B))

// select element j=lq from this lane's 4 acc regs (3 cndmask)
#define EXTRACT(V) (s1 ? (s0 ? (V)[3] : (V)[2]) : (s0 ? (V)[1] : (V)[0]))

// gates from 4 pre-scaled logits; updates c, returns h
static __device__ __forceinline__ float gate_h(float zs0, float zs1, float zs2,
                                               float zs3, float& c)
{
    const float eg = exp2f_fast(zs0), ei = exp2f_fast(zs1);
    const float ef = exp2f_fast(zs2), eo = exp2f_fast(zs3);
    const float rg = rcpf(1.0f + eg), ri = rcpf(1.0f + ei);
    const float rf = rcpf(1.0f + ef), ro = rcpf(1.0f + eo);
    const float gg = __builtin_fmaf(2.0f, rg, -1.0f);          // tanh
    const float cc = __builtin_fmaf(c, rf, gg * ri);
    c = cc;
    const float et = exp2f_fast(cc * MGC);
    const float rt = rcpf(1.0f + et);
    const float tc = __builtin_fmaf(2.0f, rt, -1.0f);
    return tc * ro;
}

// ---------------- pre-kernel: quantize + transpose Wh to int8 [gate][unit][k] ----
// h-position k holds h of unit pi(k) = (k & 0xE0) | ((k&1)<<4) | ((k>>1)&15)
__global__ __launch_bounds__(64)
void pack_w(const float* __restrict__ wg, const float* __restrict__ wi,
            const float* __restrict__ wf, const float* __restrict__ wo,
            signed char* __restrict__ wq8)
{
    const int b = blockIdx.x;            // 0..1023
    const int q = b >> 8;                // gate
    const int u = b & 255;               // unit (column)
    const float* wp = (q == 0) ? wg : (q == 1) ? wi : (q == 2) ? wf : wo;
    const int t  = threadIdx.x;          // 0..63
    const int k0 = t * 4;
    unsigned int pk = 0;
#pragma unroll
    for (int i = 0; i < 4; ++i) {
        const int k   = k0 + i;
        const int src = (k & 0xE0) | ((k & 1) << 4) | ((k >> 1) & 15);
        const float v = wp[src * HDIM + u];
        int qv = __float2int_rn(v * 127.0f);
        qv = (qv > 127) ? 127 : ((qv < -127) ? -127 : qv);
        pk |= ((unsigned int)qv & 255u) << (8 * i);
    }
    *(unsigned int*)(wq8 + ((size_t)(q * 256 + u) * 256 + k0)) = pk;
}

// ---------------- main persistent kernel ----------------------------------------
__global__ __launch_bounds__(NTHR, 2)
void lstm_full(const float* __restrict__ x,
               const float* __restrict__ w_gx, const float* __restrict__ w_ix,
               const float* __restrict__ w_fx, const float* __restrict__ w_ox,
               const float* __restrict__ b_g,  const float* __restrict__ b_i,
               const float* __restrict__ b_f,  const float* __restrict__ b_o,
               const float* __restrict__ w_ph, const float* __restrict__ b_p,
               const signed char* __restrict__ wq8,
               float* __restrict__ out)
{
    const int g    = blockIdx.x;         // 0..255, batch rows [g*4, g*4+4)
    const int tid  = threadIdx.x;
    const int w    = tid >> 6;           // wave 0..7
    const int lane = tid & 63;
    const int l16  = lane & 15;
    const int lq   = lane >> 4;          // 0..3  == this lane's batch row

    __shared__ float        x_lds[BB * XSTR];           // 2.1 KB
    __shared__ signed char  h_q[2][BB * HSTR];          // 2.5 KB
    __shared__ float        proj[BB * PSTR];            // 4.2 KB

    {   // x tile: 4 rows x 128 steps
        const float* xs = x + (size_t)g * BB * TSTEPS;
        for (int i = tid; i < BB * TSTEPS; i += NTHR)
            x_lds[(i >> 7) * XSTR + (i & 127)] = xs[i];
    }

    // ---- int8 B-fragments, pinned in AGPRs (volatile def: no sink/remat) --------
    // wave w owns units u = w*32 + ut*16 + l16 (ut=0,1), all 4 gates.
    i32x4 wa[4][2][4];
#pragma unroll
    for (int q = 0; q < 4; ++q)
#pragma unroll
        for (int ut = 0; ut < 2; ++ut) {
            const int u = w * 32 + ut * 16 + l16;
#pragma unroll
            for (int kk = 0; kk < 4; ++kk) {
                const signed char* p = wq8 + ((size_t)(q * 256 + u) * 256)
                                           + kk * 64 + lq * 16;
                i32x4 v = __builtin_bit_cast(i32x4, *(const i8x16*)p);
                asm volatile("" : "+a"(v));
                wa[q][ut][kk] = v;
            }
        }

    const float* const wxp[4] = {w_gx, w_ix, w_fx, w_ox};
    const float* const bbp[4] = {b_g, b_i, b_f, b_o};
    float wxm[4][2], bm[4][2];
#pragma unroll
    for (int q = 0; q < 4; ++q)
#pragma unroll
        for (int ut = 0; ut < 2; ++ut) {
            const int u = w * 32 + ut * 16 + l16;
            const float m = (q == 0) ? MGC : (-L2E);
            wxm[q][ut] = wxp[q][u] * m;
            bm[q][ut]  = bbp[q][u] * m;
        }

    float c0 = 0.f, c1 = 0.f;            // cell state: lane owns (row=lq, ut)
    const bool s0 = (lq & 1) != 0;
    const bool s1 = (lq & 2) != 0;
    const int  woff = lq * HSTR + w * 32 + l16 * 2;   // packed h write offset
    const int  u0 = w * 32 + l16, u1 = u0 + 16;

    __syncthreads();

    // ---- t = 0 peel: acc = 0, z = x*Wx + b only ---------------------------------
    {
        const float xv = x_lds[lq * XSTR + 0];
        float zs[2][4];
#pragma unroll
        for (int ut = 0; ut < 2; ++ut)
#pragma unroll
            for (int q = 0; q < 4; ++q)
                zs[ut][q] = __builtin_fmaf(xv, wxm[q][ut], bm[q][ut]);
        const float h0 = gate_h(zs[0][0], zs[0][1], zs[0][2], zs[0][3], c0);
        const float h1 = gate_h(zs[1][0], zs[1][1], zs[1][2], zs[1][3], c1);
        const int hq0 = __float2int_rn(h0 * 127.0f);
        const int hq1 = __float2int_rn(h1 * 127.0f);
        *(unsigned short*)(&h_q[1][woff]) =
            (unsigned short)((hq0 & 255) | ((hq1 & 255) << 8));
        __syncthreads();
    }

    // ---- main loop: t = 1 .. 127 ------------------------------------------------
    for (int t = 1; t < TSTEPS; ++t) {
        const signed char* hs = &h_q[t & 1][(l16 & 3) * HSTR];
        i32x4 ah0 = *(const i32x4*)(hs +   0 + lq * 16);
        i32x4 ah1 = *(const i32x4*)(hs +  64 + lq * 16);
        i32x4 ah2 = *(const i32x4*)(hs + 128 + lq * 16);
        i32x4 ah3 = *(const i32x4*)(hs + 192 + lq * 16);

        i32x4 a0[4] = {{0,0,0,0},{0,0,0,0},{0,0,0,0},{0,0,0,0}};
        i32x4 a1[4] = {{0,0,0,0},{0,0,0,0},{0,0,0,0},{0,0,0,0}};

        // ---- phase A: ut0's 16 MFMA --------------------------------------------
#pragma unroll
        for (int q = 0; q < 4; ++q) MFMA_I8(a0[q], ah0, wa[q][0][0]);
#pragma unroll
        for (int q = 0; q < 4; ++q) MFMA_I8(a0[q], ah1, wa[q][0][1]);
#pragma unroll
        for (int q = 0; q < 4; ++q) MFMA_I8(a0[q], ah2, wa[q][0][2]);
#pragma unroll
        for (int q = 0; q < 4; ++q) MFMA_I8(a0[q], ah3, wa[q][0][3]);

        const float xv = x_lds[lq * XSTR + t];

        // ---- phase B: ut1's 16 MFMA, chunked, with ut0 epilogue interleaved ----
#pragma unroll
        for (int q = 0; q < 4; ++q) MFMA_I8(a1[q], ah0, wa[q][1][0]);
        // chunk 0 VALU: extract + logits q0,q1 of ut0
        float zs00 = __builtin_fmaf((float)EXTRACT(a0[0]), SMG,
                     __builtin_fmaf(xv, wxm[0][0], bm[0][0]));
        float zs01 = __builtin_fmaf((float)EXTRACT(a0[1]), SMS,
                     __builtin_fmaf(xv, wxm[1][0], bm[1][0]));
#pragma unroll
        for (int q = 0; q < 4; ++q) MFMA_I8(a1[q], ah1, wa[q][1][1]);
        // chunk 1 VALU: extract + logits q2,q3 of ut0
        float zs02 = __builtin_fmaf((float)EXTRACT(a0[2]), SMS,
                     __builtin_fmaf(xv, wxm[2][0], bm[2][0]));
        float zs03 = __builtin_fmaf((float)EXTRACT(a0[3]), SMS,
                     __builtin_fmaf(xv, wxm[3][0], bm[3][0]));
#pragma unroll
        for (int q = 0; q < 4; ++q) MFMA_I8(a1[q], ah2, wa[q][1][2]);
        // chunk 2 VALU: exponentials of ut0
        const float eg0 = exp2f_fast(zs00), ei0 = exp2f_fast(zs01);
        const float ef0 = exp2f_fast(zs02), eo0 = exp2f_fast(zs03);
        const float sg0 = 1.0f + eg0, si0 = 1.0f + ei0;
        const float sf0 = 1.0f + ef0, so0 = 1.0f + eo0;
#pragma unroll
        for (int q = 0; q < 4; ++q) MFMA_I8(a1[q], ah3, wa[q][1][3]);
        // chunk 3 VALU: reciprocals + c-update of ut0
        const float rg0 = rcpf(sg0), ri0 = rcpf(si0);
        const float rf0 = rcpf(sf0), ro0 = rcpf(so0);
        const float gg0 = __builtin_fmaf(2.0f, rg0, -1.0f);
        const float cc0 = __builtin_fmaf(c0, rf0, gg0 * ri0);
        c0 = cc0;

        // ---- tails: ut0 tanh-tail overlaps ut1 extraction -----------------------
        const float et0 = exp2f_fast(cc0 * MGC);
        float zs10 = __builtin_fmaf((float)EXTRACT(a1[0]), SMG,
                     __builtin_fmaf(xv, wxm[0][1], bm[0][1]));
        float zs11 = __builtin_fmaf((float)EXTRACT(a1[1]), SMS,
                     __builtin_fmaf(xv, wxm[1][1], bm[1][1]));
        float zs12 = __builtin_fmaf((float)EXTRACT(a1[2]), SMS,
                     __builtin_fmaf(xv, wxm[2][1], bm[2][1]));
        float zs13 = __builtin_fmaf((float)EXTRACT(a1[3]), SMS,
                     __builtin_fmaf(xv, wxm[3][1], bm[3][1]));
        const float rt0 = rcpf(1.0f + et0);
        const float tc0 = __builtin_fmaf(2.0f, rt0, -1.0f);
        const float hh0 = tc0 * ro0;
        const float hh1 = gate_h(zs10, zs11, zs12, zs13, c1);

        const int hq0 = __float2int_rn(hh0 * 127.0f);
        const int hq1 = __float2int_rn(hh1 * 127.0f);
        *(unsigned short*)(&h_q[(t + 1) & 1][woff]) =
            (unsigned short)((hq0 & 255) | ((hq1 & 255) << 8));

        if (t == TSTEPS - 1) {
            proj[lq * PSTR + u0] = hh0;
            proj[lq * PSTR + u1] = hh1;
        }
        __syncthreads();
    }

    // ---- final projection: out[g*4 + r][cls], 4x10 -------------------------------
    if (tid < BB * NCLS) {
        const int r = tid / NCLS, cls = tid - r * NCLS;
        float a = b_p[cls];
#pragma unroll 8
        for (int u = 0; u < HDIM; ++u)
            a = __builtin_fmaf(proj[r * PSTR + u], w_ph[u * NCLS + cls], a);
        out[(size_t)(g * BB + r) * NCLS + cls] = a;
    }
}

extern "C" void kernel_launch(void* const* d_in, const int* in_sizes, int n_in,
                              void* d_out, int out_size, void* d_ws, size_t ws_size,
                              hipStream_t stream)
{
    const float* x    = (const float*)d_in[0];
    const float* w_gx = (const float*)d_in[1];
    const float* w_ix = (const float*)d_in[2];
    const float* w_fx = (const float*)d_in[3];
    const float* w_ox = (const float*)d_in[4];
    const float* w_gh = (const float*)d_in[5];
    const float* w_ih = (const float*)d_in[6];
    const float* w_fh = (const float*)d_in[7];
    const float* w_oh = (const float*)d_in[8];
    const float* b_g  = (const float*)d_in[9];
    const float* b_i  = (const float*)d_in[10];
    const float* b_f  = (const float*)d_in[11];
    const float* b_o  = (const float*)d_in[12];
    const float* w_ph = (const float*)d_in[13];
    const float* b_p  = (const float*)d_in[14];

    signed char* wq8 = (signed char*)d_ws;   // 4*256*256 = 256 KB

    hipLaunchKernelGGL(pack_w, dim3(1024), dim3(64), 0, stream,
                       w_gh, w_ih, w_fh, w_oh, wq8);

    hipLaunchKernelGGL(lstm_full, dim3(NBLOCKS), dim3(NTHR), 0, stream,
                       x, w_gx, w_ix, w_fx, w_ox,
                       b_g, b_i, b_f, b_o, w_ph, b_p,
                       wq8, (float*)d_out);
}

// Round 9
// 132.479 us; speedup vs baseline: 1.0216x; 1.0216x over previous
//
#include <hip/hip_runtime.h>

// LSTM: B=1024, T=128, H=256, C=10.
// Round 9: 256 blocks x 512 thr, BB=4. Wh int8 in AGPRs, inline-asm
// v_mfma_i32_16x16x64_i8 ("a" B-operand). Single int8 h (validated absmax 0.0).
// NEW vs r8: wave-slot-parity s_setprio stagger. The two co-resident waves per
// SIMD otherwise run MFMA-phase and epilogue-phase in lockstep (pipes alternate
// idle). High-prio wave drains its 32 MFMA first, then its epilogue VALU runs
// under the low-prio wave's MFMA. Slot parity from HW_REG_HW_ID (ground truth,
// independent of wave->SIMD mapping). r8's neutral source-interleave reverted.

#define TSTEPS  128
#define HDIM    256
#define NCLS    10
#define BB      4
#define NBLOCKS 256
#define NTHR    512

#define XSTR    132                 // floats per x row
#define HSTR    320                 // bytes per h row (2-way on b128 reads = free)
#define PSTR    260

typedef char  i8x16 __attribute__((ext_vector_type(16)));
typedef int   i32x4 __attribute__((ext_vector_type(4)));

#define L2E     1.4426950408889634f
#define MGC     (-2.0f * L2E)
#define SMG     (-2.0f * L2E / 16129.0f)   // acc scale, tanh gate (1/(127*127))
#define SMS     (-1.0f * L2E / 16129.0f)   // acc scale, sigmoid gates

static __device__ __forceinline__ float rcpf(float x) { return __builtin_amdgcn_rcpf(x); }
static __device__ __forceinline__ float exp2f_fast(float x) { return __builtin_amdgcn_exp2f(x); }

#define MFMA_I8(ACC, A, B) \
    asm("v_mfma_i32_16x16x64_i8 %0, %1, %2, %0" : "+v"(ACC) : "v"(A), "a"(B))

// select element j=lq from this lane's 4 acc regs (3 cndmask)
#define EXTRACT(V) (s1 ? (s0 ? (V)[3] : (V)[2]) : (s0 ? (V)[1] : (V)[0]))

// gates from 4 pre-scaled logits; updates c, returns h
static __device__ __forceinline__ float gate_h(float zs0, float zs1, float zs2,
                                               float zs3, float& c)
{
    const float eg = exp2f_fast(zs0), ei = exp2f_fast(zs1);
    const float ef = exp2f_fast(zs2), eo = exp2f_fast(zs3);
    const float rg = rcpf(1.0f + eg), ri = rcpf(1.0f + ei);
    const float rf = rcpf(1.0f + ef), ro = rcpf(1.0f + eo);
    const float gg = __builtin_fmaf(2.0f, rg, -1.0f);          // tanh
    const float cc = __builtin_fmaf(c, rf, gg * ri);
    c = cc;
    const float et = exp2f_fast(cc * MGC);
    const float rt = rcpf(1.0f + et);
    const float tc = __builtin_fmaf(2.0f, rt, -1.0f);
    return tc * ro;
}

// ---------------- pre-kernel: quantize + transpose Wh to int8 [gate][unit][k] ----
// h-position k holds h of unit pi(k) = (k & 0xE0) | ((k&1)<<4) | ((k>>1)&15)
__global__ __launch_bounds__(64)
void pack_w(const float* __restrict__ wg, const float* __restrict__ wi,
            const float* __restrict__ wf, const float* __restrict__ wo,
            signed char* __restrict__ wq8)
{
    const int b = blockIdx.x;            // 0..1023
    const int q = b >> 8;                // gate
    const int u = b & 255;               // unit (column)
    const float* wp = (q == 0) ? wg : (q == 1) ? wi : (q == 2) ? wf : wo;
    const int t  = threadIdx.x;          // 0..63
    const int k0 = t * 4;
    unsigned int pk = 0;
#pragma unroll
    for (int i = 0; i < 4; ++i) {
        const int k   = k0 + i;
        const int src = (k & 0xE0) | ((k & 1) << 4) | ((k >> 1) & 15);
        const float v = wp[src * HDIM + u];
        int qv = __float2int_rn(v * 127.0f);
        qv = (qv > 127) ? 127 : ((qv < -127) ? -127 : qv);
        pk |= ((unsigned int)qv & 255u) << (8 * i);
    }
    *(unsigned int*)(wq8 + ((size_t)(q * 256 + u) * 256 + k0)) = pk;
}

// ---------------- main persistent kernel ----------------------------------------
__global__ __launch_bounds__(NTHR, 2)
void lstm_full(const float* __restrict__ x,
               const float* __restrict__ w_gx, const float* __restrict__ w_ix,
               const float* __restrict__ w_fx, const float* __restrict__ w_ox,
               const float* __restrict__ b_g,  const float* __restrict__ b_i,
               const float* __restrict__ b_f,  const float* __restrict__ b_o,
               const float* __restrict__ w_ph, const float* __restrict__ b_p,
               const signed char* __restrict__ wq8,
               float* __restrict__ out)
{
    const int g    = blockIdx.x;         // 0..255, batch rows [g*4, g*4+4)
    const int tid  = threadIdx.x;
    const int w    = tid >> 6;           // wave 0..7
    const int lane = tid & 63;
    const int l16  = lane & 15;
    const int lq   = lane >> 4;          // 0..3  == this lane's batch row

    __shared__ float        x_lds[BB * XSTR];           // 2.1 KB
    __shared__ signed char  h_q[2][BB * HSTR];          // 2.5 KB
    __shared__ float        proj[BB * PSTR];            // 4.2 KB

    {   // x tile: 4 rows x 128 steps
        const float* xs = x + (size_t)g * BB * TSTEPS;
        for (int i = tid; i < BB * TSTEPS; i += NTHR)
            x_lds[(i >> 7) * XSTR + (i & 127)] = xs[i];
    }

    // wave slot within SIMD (HW_REG_HW_ID bits [3:0]); co-resident waves on a
    // SIMD occupy different slots -> parity gives one hi-prio wave per SIMD.
    unsigned hwid;
    asm volatile("s_getreg_b32 %0, hwreg(HW_REG_HW_ID, 0, 4)" : "=s"(hwid));
    const bool hiprio = (hwid & 1u) == 0u;

    // ---- int8 B-fragments, pinned in AGPRs (volatile def: no sink/remat) --------
    // wave w owns units u = w*32 + ut*16 + l16 (ut=0,1), all 4 gates.
    i32x4 wa[4][2][4];
#pragma unroll
    for (int q = 0; q < 4; ++q)
#pragma unroll
        for (int ut = 0; ut < 2; ++ut) {
            const int u = w * 32 + ut * 16 + l16;
#pragma unroll
            for (int kk = 0; kk < 4; ++kk) {
                const signed char* p = wq8 + ((size_t)(q * 256 + u) * 256)
                                           + kk * 64 + lq * 16;
                i32x4 v = __builtin_bit_cast(i32x4, *(const i8x16*)p);
                asm volatile("" : "+a"(v));
                wa[q][ut][kk] = v;
            }
        }

    const float* const wxp[4] = {w_gx, w_ix, w_fx, w_ox};
    const float* const bbp[4] = {b_g, b_i, b_f, b_o};
    float wxm[4][2], bm[4][2];
#pragma unroll
    for (int q = 0; q < 4; ++q)
#pragma unroll
        for (int ut = 0; ut < 2; ++ut) {
            const int u = w * 32 + ut * 16 + l16;
            const float m = (q == 0) ? MGC : (-L2E);
            wxm[q][ut] = wxp[q][u] * m;
            bm[q][ut]  = bbp[q][u] * m;
        }

    float c0 = 0.f, c1 = 0.f;            // cell state: lane owns (row=lq, ut)
    const bool s0 = (lq & 1) != 0;
    const bool s1 = (lq & 2) != 0;
    const int  woff = lq * HSTR + w * 32 + l16 * 2;   // packed h write offset
    const int  u0 = w * 32 + l16, u1 = u0 + 16;

    __syncthreads();

    // ---- t = 0 peel: acc = 0, z = x*Wx + b only ---------------------------------
    {
        const float xv = x_lds[lq * XSTR + 0];
        float zs[2][4];
#pragma unroll
        for (int ut = 0; ut < 2; ++ut)
#pragma unroll
            for (int q = 0; q < 4; ++q)
                zs[ut][q] = __builtin_fmaf(xv, wxm[q][ut], bm[q][ut]);
        const float h0 = gate_h(zs[0][0], zs[0][1], zs[0][2], zs[0][3], c0);
        const float h1 = gate_h(zs[1][0], zs[1][1], zs[1][2], zs[1][3], c1);
        const int hq0 = __float2int_rn(h0 * 127.0f);
        const int hq1 = __float2int_rn(h1 * 127.0f);
        *(unsigned short*)(&h_q[1][woff]) =
            (unsigned short)((hq0 & 255) | ((hq1 & 255) << 8));
        __syncthreads();
    }

    // ---- main loop: t = 1 .. 127 ------------------------------------------------
    for (int t = 1; t < TSTEPS; ++t) {
        const signed char* hs = &h_q[t & 1][(l16 & 3) * HSTR];
        i32x4 ah0 = *(const i32x4*)(hs +   0 + lq * 16);
        i32x4 ah1 = *(const i32x4*)(hs +  64 + lq * 16);
        i32x4 ah2 = *(const i32x4*)(hs + 128 + lq * 16);
        i32x4 ah3 = *(const i32x4*)(hs + 192 + lq * 16);

        i32x4 a0[4] = {{0,0,0,0},{0,0,0,0},{0,0,0,0},{0,0,0,0}};
        i32x4 a1[4] = {{0,0,0,0},{0,0,0,0},{0,0,0,0},{0,0,0,0}};

        // ---- MFMA phase: hi-prio wave drains first, lo-prio wave's continues
        // under the hi-prio wave's epilogue ----------------------------------
        if (hiprio) __builtin_amdgcn_s_setprio(1);
#pragma unroll
        for (int kk = 0; kk < 4; ++kk) {
            const i32x4 ah = (kk == 0) ? ah0 : (kk == 1) ? ah1 : (kk == 2) ? ah2 : ah3;
#pragma unroll
            for (int q = 0; q < 4; ++q) {
                MFMA_I8(a0[q], ah, wa[q][0][kk]);
                MFMA_I8(a1[q], ah, wa[q][1][kk]);
            }
        }
        if (hiprio) __builtin_amdgcn_s_setprio(0);

        // ---- epilogue: lane handles (row=lq, units u0,u1) -----------------------
        const float xv = x_lds[lq * XSTR + t];
        float zs00 = __builtin_fmaf((float)EXTRACT(a0[0]), SMG,
                     __builtin_fmaf(xv, wxm[0][0], bm[0][0]));
        float zs01 = __builtin_fmaf((float)EXTRACT(a0[1]), SMS,
                     __builtin_fmaf(xv, wxm[1][0], bm[1][0]));
        float zs02 = __builtin_fmaf((float)EXTRACT(a0[2]), SMS,
                     __builtin_fmaf(xv, wxm[2][0], bm[2][0]));
        float zs03 = __builtin_fmaf((float)EXTRACT(a0[3]), SMS,
                     __builtin_fmaf(xv, wxm[3][0], bm[3][0]));
        float zs10 = __builtin_fmaf((float)EXTRACT(a1[0]), SMG,
                     __builtin_fmaf(xv, wxm[0][1], bm[0][1]));
        float zs11 = __builtin_fmaf((float)EXTRACT(a1[1]), SMS,
                     __builtin_fmaf(xv, wxm[1][1], bm[1][1]));
        float zs12 = __builtin_fmaf((float)EXTRACT(a1[2]), SMS,
                     __builtin_fmaf(xv, wxm[2][1], bm[2][1]));
        float zs13 = __builtin_fmaf((float)EXTRACT(a1[3]), SMS,
                     __builtin_fmaf(xv, wxm[3][1], bm[3][1]));

        const float hh0 = gate_h(zs00, zs01, zs02, zs03, c0);
        const float hh1 = gate_h(zs10, zs11, zs12, zs13, c1);

        const int hq0 = __float2int_rn(hh0 * 127.0f);
        const int hq1 = __float2int_rn(hh1 * 127.0f);
        *(unsigned short*)(&h_q[(t + 1) & 1][woff]) =
            (unsigned short)((hq0 & 255) | ((hq1 & 255) << 8));

        if (t == TSTEPS - 1) {
            proj[lq * PSTR + u0] = hh0;
            proj[lq * PSTR + u1] = hh1;
        }
        __syncthreads();
    }

    // ---- final projection: out[g*4 + r][cls], 4x10 -------------------------------
    if (tid < BB * NCLS) {
        const int r = tid / NCLS, cls = tid - r * NCLS;
        float a = b_p[cls];
#pragma unroll 8
        for (int u = 0; u < HDIM; ++u)
            a = __builtin_fmaf(proj[r * PSTR + u], w_ph[u * NCLS + cls], a);
        out[(size_t)(g * BB + r) * NCLS + cls] = a;
    }
}

extern "C" void kernel_launch(void* const* d_in, const int* in_sizes, int n_in,
                              void* d_out, int out_size, void* d_ws, size_t ws_size,
                              hipStream_t stream)
{
    const float* x    = (const float*)d_in[0];
    const float* w_gx = (const float*)d_in[1];
    const float* w_ix = (const float*)d_in[2];
    const float* w_fx = (const float*)d_in[3];
    const float* w_ox = (const float*)d_in[4];
    const float* w_gh = (const float*)d_in[5];
    const float* w_ih = (const float*)d_in[6];
    const float* w_fh = (const float*)d_in[7];
    const float* w_oh = (const float*)d_in[8];
    const float* b_g  = (const float*)d_in[9];
    const float* b_i  = (const float*)d_in[10];
    const float* b_f  = (const float*)d_in[11];
    const float* b_o  = (const float*)d_in[12];
    const float* w_ph = (const float*)d_in[13];
    const float* b_p  = (const float*)d_in[14];

    signed char* wq8 = (signed char*)d_ws;   // 4*256*256 = 256 KB

    hipLaunchKernelGGL(pack_w, dim3(1024), dim3(64), 0, stream,
                       w_gh, w_ih, w_fh, w_oh, wq8);

    hipLaunchKernelGGL(lstm_full, dim3(NBLOCKS), dim3(NTHR), 0, stream,
                       x, w_gx, w_ix, w_fx, w_ox,
                       b_g, b_i, b_f, b_o, w_ph, b_p,
                       wq8, (float*)d_out);
}

// Round 10
// 124.765 us; speedup vs baseline: 1.0847x; 1.0618x over previous
//
#include <hip/hip_runtime.h>

// LSTM: B=1024, T=128, H=256, C=10.
// Round 10: 256 blocks x 1024 thr (16 waves), BB=4. Each wave owns 16 hidden
// units x 4 gates: 64 weight AGPRs + ~60 VGPRs ~= 124/wave -> 4 waves/SIMD
// (double round 9's occupancy) so ds/gate/barrier latency hides under other
// waves' MFMA. Per-SIMD MFMA issue unchanged (64/step = B-coverage floor).
// Wh int8 pinned in AGPRs, inline-asm v_mfma_i32_16x16x64_i8 ("a" B-operand).
// Single int8 h (validated absmax 0.0). One output per lane in the epilogue.

#define TSTEPS  128
#define HDIM    256
#define NCLS    10
#define BB      4
#define NBLOCKS 256
#define NTHR    1024

#define XSTR    132                 // floats per x row
#define HSTR    320                 // bytes per h row (2-way on b128 reads = free)
#define PSTR    260

typedef char  i8x16 __attribute__((ext_vector_type(16)));
typedef int   i32x4 __attribute__((ext_vector_type(4)));

#define L2E     1.4426950408889634f
#define MGC     (-2.0f * L2E)
#define SMG     (-2.0f * L2E / 16129.0f)   // acc scale, tanh gate (1/(127*127))
#define SMS     (-1.0f * L2E / 16129.0f)   // acc scale, sigmoid gates

static __device__ __forceinline__ float rcpf(float x) { return __builtin_amdgcn_rcpf(x); }
static __device__ __forceinline__ float exp2f_fast(float x) { return __builtin_amdgcn_exp2f(x); }

#define MFMA_I8(ACC, A, B) \
    asm("v_mfma_i32_16x16x64_i8 %0, %1, %2, %0" : "+v"(ACC) : "v"(A), "a"(B))

// select element j=lq from this lane's 4 acc regs (3 cndmask)
#define EXTRACT(V) (s1 ? (s0 ? (V)[3] : (V)[2]) : (s0 ? (V)[1] : (V)[0]))

// gates from 4 pre-scaled logits; updates c, returns h
static __device__ __forceinline__ float gate_h(float zs0, float zs1, float zs2,
                                               float zs3, float& c)
{
    const float eg = exp2f_fast(zs0), ei = exp2f_fast(zs1);
    const float ef = exp2f_fast(zs2), eo = exp2f_fast(zs3);
    const float rg = rcpf(1.0f + eg), ri = rcpf(1.0f + ei);
    const float rf = rcpf(1.0f + ef), ro = rcpf(1.0f + eo);
    const float gg = __builtin_fmaf(2.0f, rg, -1.0f);          // tanh
    const float cc = __builtin_fmaf(c, rf, gg * ri);
    c = cc;
    const float et = exp2f_fast(cc * MGC);
    const float rt = rcpf(1.0f + et);
    const float tc = __builtin_fmaf(2.0f, rt, -1.0f);
    return tc * ro;
}

// ---------------- pre-kernel: quantize + transpose Wh to int8 [gate][unit][k] ----
__global__ __launch_bounds__(64)
void pack_w(const float* __restrict__ wg, const float* __restrict__ wi,
            const float* __restrict__ wf, const float* __restrict__ wo,
            signed char* __restrict__ wq8)
{
    const int b = blockIdx.x;            // 0..1023
    const int q = b >> 8;                // gate
    const int u = b & 255;               // unit (column)
    const float* wp = (q == 0) ? wg : (q == 1) ? wi : (q == 2) ? wf : wo;
    const int t  = threadIdx.x;          // 0..63
    const int k0 = t * 4;
    unsigned int pk = 0;
#pragma unroll
    for (int i = 0; i < 4; ++i) {
        const float v = wp[(k0 + i) * HDIM + u];
        int qv = __float2int_rn(v * 127.0f);
        qv = (qv > 127) ? 127 : ((qv < -127) ? -127 : qv);
        pk |= ((unsigned int)qv & 255u) << (8 * i);
    }
    *(unsigned int*)(wq8 + ((size_t)(q * 256 + u) * 256 + k0)) = pk;
}

// ---------------- main persistent kernel ----------------------------------------
__global__ __launch_bounds__(NTHR, 4)
void lstm_full(const float* __restrict__ x,
               const float* __restrict__ w_gx, const float* __restrict__ w_ix,
               const float* __restrict__ w_fx, const float* __restrict__ w_ox,
               const float* __restrict__ b_g,  const float* __restrict__ b_i,
               const float* __restrict__ b_f,  const float* __restrict__ b_o,
               const float* __restrict__ w_ph, const float* __restrict__ b_p,
               const signed char* __restrict__ wq8,
               float* __restrict__ out)
{
    const int g    = blockIdx.x;         // 0..255, batch rows [g*4, g*4+4)
    const int tid  = threadIdx.x;
    const int w    = tid >> 6;           // wave 0..15
    const int lane = tid & 63;
    const int l16  = lane & 15;
    const int lq   = lane >> 4;          // 0..3  == this lane's batch row

    __shared__ float        x_lds[BB * XSTR];           // 2.1 KB
    __shared__ signed char  h_q[2][BB * HSTR];          // 2.5 KB
    __shared__ float        proj[BB * PSTR];            // 4.2 KB

    {   // x tile: 4 rows x 128 steps
        const float* xs = x + (size_t)g * BB * TSTEPS;
        for (int i = tid; i < BB * TSTEPS; i += NTHR)
            x_lds[(i >> 7) * XSTR + (i & 127)] = xs[i];
    }

    // ---- int8 B-fragments, pinned in AGPRs (volatile def: no sink/remat) --------
    // wave w owns units u = w*16 + l16 (ONE unit per lane), all 4 gates.
    // element e of lane (l16,lq), chunk kk: B[k = kk*64+lq*16+e][u]
    const int u = w * 16 + l16;
    i32x4 wa[4][4];
#pragma unroll
    for (int q = 0; q < 4; ++q)
#pragma unroll
        for (int kk = 0; kk < 4; ++kk) {
            const signed char* p = wq8 + ((size_t)(q * 256 + u) * 256)
                                       + kk * 64 + lq * 16;
            i32x4 v = __builtin_bit_cast(i32x4, *(const i8x16*)p);
            asm volatile("" : "+a"(v));
            wa[q][kk] = v;
        }

    const float* const wxp[4] = {w_gx, w_ix, w_fx, w_ox};
    const float* const bbp[4] = {b_g, b_i, b_f, b_o};
    float wxm[4], bm[4];
#pragma unroll
    for (int q = 0; q < 4; ++q) {
        const float m = (q == 0) ? MGC : (-L2E);
        wxm[q] = wxp[q][u] * m;
        bm[q]  = bbp[q][u] * m;
    }

    float c = 0.f;                       // cell state: lane owns (row=lq, unit u)
    const bool s0 = (lq & 1) != 0;
    const bool s1 = (lq & 2) != 0;
    const int  woff = lq * HSTR + u;     // h write offset (1 byte per lane)

    __syncthreads();

    // ---- t = 0 peel: acc = 0, z = x*Wx + b only ---------------------------------
    {
        const float xv = x_lds[lq * XSTR + 0];
        const float hh = gate_h(__builtin_fmaf(xv, wxm[0], bm[0]),
                                __builtin_fmaf(xv, wxm[1], bm[1]),
                                __builtin_fmaf(xv, wxm[2], bm[2]),
                                __builtin_fmaf(xv, wxm[3], bm[3]), c);
        h_q[1][woff] = (signed char)__float2int_rn(hh * 127.0f);
        __syncthreads();
    }

    // ---- main loop: t = 1 .. 127 ------------------------------------------------
    for (int t = 1; t < TSTEPS; ++t) {
        const signed char* hs = &h_q[t & 1][(l16 & 3) * HSTR];
        const i32x4 ah0 = *(const i32x4*)(hs +   0 + lq * 16);
        const i32x4 ah1 = *(const i32x4*)(hs +  64 + lq * 16);
        const i32x4 ah2 = *(const i32x4*)(hs + 128 + lq * 16);
        const i32x4 ah3 = *(const i32x4*)(hs + 192 + lq * 16);

        i32x4 a[4] = {{0,0,0,0},{0,0,0,0},{0,0,0,0},{0,0,0,0}};
#pragma unroll
        for (int q = 0; q < 4; ++q) MFMA_I8(a[q], ah0, wa[q][0]);
#pragma unroll
        for (int q = 0; q < 4; ++q) MFMA_I8(a[q], ah1, wa[q][1]);
#pragma unroll
        for (int q = 0; q < 4; ++q) MFMA_I8(a[q], ah2, wa[q][2]);
#pragma unroll
        for (int q = 0; q < 4; ++q) MFMA_I8(a[q], ah3, wa[q][3]);

        // epilogue: ONE output per lane (row=lq, unit u); acc j=lq via selects
        const float xv = x_lds[lq * XSTR + t];
        const float zs0 = __builtin_fmaf((float)EXTRACT(a[0]), SMG,
                          __builtin_fmaf(xv, wxm[0], bm[0]));
        const float zs1 = __builtin_fmaf((float)EXTRACT(a[1]), SMS,
                          __builtin_fmaf(xv, wxm[1], bm[1]));
        const float zs2 = __builtin_fmaf((float)EXTRACT(a[2]), SMS,
                          __builtin_fmaf(xv, wxm[2], bm[2]));
        const float zs3 = __builtin_fmaf((float)EXTRACT(a[3]), SMS,
                          __builtin_fmaf(xv, wxm[3], bm[3]));
        const float hh = gate_h(zs0, zs1, zs2, zs3, c);

        h_q[(t + 1) & 1][woff] = (signed char)__float2int_rn(hh * 127.0f);
        if (t == TSTEPS - 1) proj[lq * PSTR + u] = hh;
        __syncthreads();
    }

    // ---- final projection: out[g*4 + r][cls], 4x10 -------------------------------
    if (tid < BB * NCLS) {
        const int r = tid / NCLS, cls = tid - r * NCLS;
        float a = b_p[cls];
#pragma unroll 8
        for (int uu = 0; uu < HDIM; ++uu)
            a = __builtin_fmaf(proj[r * PSTR + uu], w_ph[uu * NCLS + cls], a);
        out[(size_t)(g * BB + r) * NCLS + cls] = a;
    }
}

extern "C" void kernel_launch(void* const* d_in, const int* in_sizes, int n_in,
                              void* d_out, int out_size, void* d_ws, size_t ws_size,
                              hipStream_t stream)
{
    const float* x    = (const float*)d_in[0];
    const float* w_gx = (const float*)d_in[1];
    const float* w_ix = (const float*)d_in[2];
    const float* w_fx = (const float*)d_in[3];
    const float* w_ox = (const float*)d_in[4];
    const float* w_gh = (const float*)d_in[5];
    const float* w_ih = (const float*)d_in[6];
    const float* w_fh = (const float*)d_in[7];
    const float* w_oh = (const float*)d_in[8];
    const float* b_g  = (const float*)d_in[9];
    const float* b_i  = (const float*)d_in[10];
    const float* b_f  = (const float*)d_in[11];
    const float* b_o  = (const float*)d_in[12];
    const float* w_ph = (const float*)d_in[13];
    const float* b_p  = (const float*)d_in[14];

    signed char* wq8 = (signed char*)d_ws;   // 4*256*256 = 256 KB

    hipLaunchKernelGGL(pack_w, dim3(1024), dim3(64), 0, stream,
                       w_gh, w_ih, w_fh, w_oh, wq8);

    hipLaunchKernelGGL(lstm_full, dim3(NBLOCKS), dim3(NTHR), 0, stream,
                       x, w_gx, w_ix, w_fx, w_ox,
                       b_g, b_i, b_f, b_o, w_ph, b_p,
                       wq8, (float*)d_out);
}